// Round 4
// baseline (67.191 us; speedup 1.0000x reference)
//
#include <hip/hip_runtime.h>
#include <math.h>

namespace {
constexpr int NB   = 8;    // batch
constexpr int NWIN = 128;  // WIN
constexpr int NK   = 256;  // K (feature/attention dim)
constexpr int NE   = 256;  // E = 2*WIN

// ---------------------------------------------------------------------------
// Kernel 1: projections (unchanged from round 3 — keeps C term constant).
// ---------------------------------------------------------------------------
__global__ __launch_bounds__(1024) void k1_proj(
    const float* __restrict__ x, const float* __restrict__ W,
    const float* __restrict__ bl, float* __restrict__ hi,
    float* __restrict__ hjT)
{
  __shared__ float red[3][8][NK];  // 24 KB

  const int b  = blockIdx.x >> 5;
  const int e0 = (blockIdx.x & 31) << 3;
  const int t  = threadIdx.x;
  const int i  = t & 255;
  const int q  = t >> 8;  // w-quarter, 0..3

  float acc1[8], acc2[8];
#pragma unroll
  for (int et = 0; et < 8; ++et) { acc1[et] = 0.f; acc2[et] = 0.f; }

  const float* xb = x + (size_t)b * NWIN * NK + i;
  const float* Wr = W + (size_t)e0 * (2 * NWIN);
#pragma unroll 8
  for (int wi = 0; wi < 32; ++wi) {
    const int w = q * 32 + wi;
    const float xv = xb[(size_t)w * NK];
#pragma unroll
    for (int et = 0; et < 8; ++et) {
      acc1[et] = fmaf(xv, Wr[et * 2 * NWIN + w], acc1[et]);
      acc2[et] = fmaf(xv, Wr[et * 2 * NWIN + NWIN + w], acc2[et]);
    }
  }

  if (q) {
#pragma unroll
    for (int et = 0; et < 8; ++et) red[q - 1][et][i] = acc1[et];
  }
  __syncthreads();
  if (q == 0) {
    float* hp = hi + ((size_t)(b * NK + i)) * NE + e0;
#pragma unroll
    for (int et = 0; et < 8; ++et)
      hp[et] = acc1[et] + red[0][et][i] + red[1][et][i] + red[2][et][i];
  }
  __syncthreads();
  if (q) {
#pragma unroll
    for (int et = 0; et < 8; ++et) red[q - 1][et][i] = acc2[et];
  }
  __syncthreads();
  if (q == 0) {
#pragma unroll
    for (int et = 0; et < 8; ++et)
      hjT[((size_t)(b * NE + e0 + et)) * NK + i] =
          acc2[et] + red[0][et][i] + red[1][et][i] + red[2][et][i] + bl[e0 + et];
  }
}

// ---------------------------------------------------------------------------
// Kernel 2: unchanged from round 3. Launched TWICE this round (idempotent)
// to measure K2 = D4 - D3 and C = 2*D3 - D4.
// ---------------------------------------------------------------------------
__global__ __launch_bounds__(512) void k2_attn(
    const float* __restrict__ x, const float* __restrict__ a_vec,
    const float* __restrict__ bias, const float* __restrict__ hi,
    const float* __restrict__ hjT, float* __restrict__ out)
{
  __shared__ __align__(16) float smA[2312];   // 9.2 KB
  __shared__ __align__(16) float smB[18432];  // 72 KB

  const int b    = blockIdx.x >> 5;
  const int i0   = (blockIdx.x & 31) << 3;
  const int t    = threadIdx.x;
  const int lane = t & 63, wave = t >> 6;

  // ---- stage hi tile (2048 contiguous floats) + 0.8*a ----
  {
    const float4* src = (const float4*)(hi + ((size_t)(b * NK + i0)) * NE);
    ((float4*)smA)[t] = src[t];
    if (t < 64) {
      const float4 av = ((const float4*)a_vec)[t];
      ((float4*)(smA + 2048))[t] =
          make_float4(0.8f * av.x, 0.8f * av.y, 0.8f * av.z, 0.8f * av.w);
    }
  }
  __syncthreads();

  // ---- ai8 per row: wave = row ----
  {
    float p = 0.f;
#pragma unroll
    for (int r = 0; r < 4; ++r) {
      const int e = lane + r * 64;
      p = fmaf(smA[2048 + e], smA[wave * NE + e], p);
    }
#pragma unroll
    for (int o = 32; o; o >>= 1) p += __shfl_xor(p, o);
    if (lane == 0) smA[2304 + wave] = p;
  }

  // ---- main relu-term loop: 4 contiguous j per thread, e-eighth per wave ----
  {
    const int q = wave;
    const int j0 = lane << 2;
    float s[8][4];
#pragma unroll
    for (int ii = 0; ii < 8; ++ii)
#pragma unroll
      for (int m = 0; m < 4; ++m) s[ii][m] = 0.f;
    float aj[4] = {0.f, 0.f, 0.f, 0.f};

    const float* hjb = hjT + (size_t)b * NE * NK + j0;

#pragma unroll 2
    for (int ec = 0; ec < 8; ++ec) {
      const int e = q * 32 + ec * 4;
      float h[4][4];  // [k = e-offset][m = j-offset]
#pragma unroll
      for (int k = 0; k < 4; ++k)
        *reinterpret_cast<float4*>(h[k]) =
            *reinterpret_cast<const float4*>(hjb + (size_t)(e + k) * NK);
      float a4[4];
      *reinterpret_cast<float4*>(a4) =
          *reinterpret_cast<const float4*>(smA + 2048 + e);
#pragma unroll
      for (int k = 0; k < 4; ++k)
#pragma unroll
        for (int m = 0; m < 4; ++m) aj[m] = fmaf(a4[k], h[k][m], aj[m]);
#pragma unroll
      for (int ii = 0; ii < 8; ++ii) {
        float g[4];
        *reinterpret_cast<float4*>(g) =
            *reinterpret_cast<const float4*>(smA + ii * NE + e);
#pragma unroll
        for (int k = 0; k < 4; ++k)
#pragma unroll
          for (int m = 0; m < 4; ++m)
            s[ii][m] = fmaf(a4[k], fmaxf(g[k] + h[k][m], 0.f), s[ii][m]);
      }
    }

#pragma unroll
    for (int ii = 0; ii < 8; ++ii)
      *reinterpret_cast<float4*>(&smB[(q * 8 + ii) * NK + j0]) =
          make_float4(s[ii][0], s[ii][1], s[ii][2], s[ii][3]);
    *reinterpret_cast<float4*>(&smB[16384 + q * NK + j0]) =
        make_float4(aj[0], aj[1], aj[2], aj[3]);
  }
  __syncthreads();

  // ---- softmax over j: wave = row ----
  {
    const int ii = wave;
    const float ai = smA[2304 + ii];
    float ev[4];
    float mmax = -INFINITY;
#pragma unroll
    for (int r = 0; r < 4; ++r) {
      const int jj = lane + 64 * r;
      float v = 0.f, ajs = 0.f;
#pragma unroll
      for (int qq = 0; qq < 8; ++qq) {
        v += smB[(qq * 8 + ii) * NK + jj];
        ajs += smB[16384 + qq * NK + jj];
      }
      v += 0.25f * (ai + ajs) + bias[(size_t)(i0 + ii) * NK + jj];
      ev[r] = v;
      mmax = fmaxf(mmax, v);
    }
#pragma unroll
    for (int o = 32; o; o >>= 1) mmax = fmaxf(mmax, __shfl_xor(mmax, o));
    float ssum = 0.f;
#pragma unroll
    for (int r = 0; r < 4; ++r) { ev[r] = __expf(ev[r] - mmax); ssum += ev[r]; }
#pragma unroll
    for (int o = 32; o; o >>= 1) ssum += __shfl_xor(ssum, o);
    const float inv = 1.f / ssum;
#pragma unroll
    for (int r = 0; r < 4; ++r) smA[ii * NE + lane + 64 * r] = ev[r] * inv;
  }
  __syncthreads();

  // ---- PV: thread = (wq = t&31 -> 4 w's, q16 = t>>5 -> 16 j's) ----
  {
    const int wq = t & 31, q16 = t >> 5;
    float acc[4][8];
#pragma unroll
    for (int m = 0; m < 4; ++m)
#pragma unroll
      for (int ii = 0; ii < 8; ++ii) acc[m][ii] = 0.f;
    const float* xb = x + (size_t)b * NWIN * NK;

#pragma unroll
    for (int jc = 0; jc < 4; ++jc) {
      const int j4 = q16 * 16 + jc * 4;
      float xv[4][4];
#pragma unroll
      for (int m = 0; m < 4; ++m)
        *reinterpret_cast<float4*>(xv[m]) = *reinterpret_cast<const float4*>(
            xb + (size_t)(wq + 32 * m) * NK + j4);
#pragma unroll
      for (int ii = 0; ii < 8; ++ii) {
        float at[4];
        *reinterpret_cast<float4*>(at) =
            *reinterpret_cast<const float4*>(smA + ii * NE + j4);
#pragma unroll
        for (int m = 0; m < 4; ++m)
#pragma unroll
          for (int k = 0; k < 4; ++k)
            acc[m][ii] = fmaf(at[k], xv[m][k], acc[m][ii]);
      }
    }
#pragma unroll
    for (int ii = 0; ii < 8; ++ii)
#pragma unroll
      for (int m = 0; m < 4; ++m)
        smB[(q16 * 8 + ii) * NWIN + wq + 32 * m] = acc[m][ii];
  }
  __syncthreads();

  // ---- final reduce + sigmoid + store ----
#pragma unroll
  for (int off = 0; off < 2; ++off) {
    const int idx = t + off * 512;
    const int w = idx & 127, ii = idx >> 7;
    float v = 0.f;
#pragma unroll
    for (int qq = 0; qq < 16; ++qq) v += smB[(qq * 8 + ii) * NWIN + w];
    out[((size_t)(b * NWIN + w)) * NK + i0 + ii] = 1.f / (1.f + __expf(-v));
  }
}

}  // namespace

extern "C" void kernel_launch(void* const* d_in, const int* in_sizes, int n_in,
                              void* d_out, int out_size, void* d_ws,
                              size_t ws_size, hipStream_t stream)
{
  const float* x    = (const float*)d_in[0];  // (8,128,256)
  const float* Wlin = (const float*)d_in[1];  // (256,256)
  const float* blin = (const float*)d_in[2];  // (256,)
  const float* avec = (const float*)d_in[3];  // (256,1)
  const float* bias = (const float*)d_in[4];  // (256,256)
  float* out = (float*)d_out;                 // (8,128,256)

  float* hi  = (float*)d_ws;                   // B*K*E floats = 2 MB
  float* hjT = hi + (size_t)NB * NK * NE;      // B*E*K floats = 2 MB

  k1_proj<<<NB * (NE / 8), 1024, 0, stream>>>(x, Wlin, blin, hi, hjT);
  // k2 launched twice (idempotent): D4 = C + 2*K2 vs round-3's D3 = C + K2.
  // => K2 = D4 - D3, C = 2*D3 - D4. Attribution probe.
  k2_attn<<<NB * (NK / 8), 512, 0, stream>>>(x, avec, bias, hi, hjT, out);
  k2_attn<<<NB * (NK / 8), 512, 0, stream>>>(x, avec, bias, hi, hjT, out);
}

// Round 6
// 45.987 us; speedup vs baseline: 1.4611x; 1.4611x over previous
//
#include <hip/hip_runtime.h>
#include <math.h>

namespace {
constexpr int NB   = 8;    // batch
constexpr int NWIN = 128;  // WIN
constexpr int NK   = 256;  // K (feature/attention dim)
constexpr int NE   = 256;  // E = 2*WIN

// ---------------------------------------------------------------------------
// Kernel 1: projections. e-tile 4, 512 blocks x 256 threads (2 waves/SIMD).
//   hi [b][i][e] = sum_w x[b][w][i] * W_lin[e][w]
//   hjT[b][e][j] = sum_w x[b][w][j] * W_lin[e][WIN+w] + b_lin[e]
// x loads lane-coalesced; W loads block-uniform (scalar).
// ---------------------------------------------------------------------------
__global__ __launch_bounds__(256) void k1_proj(
    const float* __restrict__ x, const float* __restrict__ W,
    const float* __restrict__ bl, float* __restrict__ hi,
    float* __restrict__ hjT)
{
  const int b  = blockIdx.x >> 6;          // 0..7
  const int e0 = (blockIdx.x & 63) << 2;   // 64 groups of 4 e's
  const int i  = threadIdx.x;

  float acc1[4] = {0.f, 0.f, 0.f, 0.f};
  float acc2[4] = {0.f, 0.f, 0.f, 0.f};

  const float* xb = x + (size_t)b * NWIN * NK + i;
  const float* Wr = W + (size_t)e0 * (2 * NWIN);
#pragma unroll 8
  for (int w = 0; w < NWIN; ++w) {
    const float xv = xb[(size_t)w * NK];
#pragma unroll
    for (int k = 0; k < 4; ++k) {
      acc1[k] = fmaf(xv, Wr[k * 2 * NWIN + w], acc1[k]);
      acc2[k] = fmaf(xv, Wr[k * 2 * NWIN + NWIN + w], acc2[k]);
    }
  }

  *reinterpret_cast<float4*>(hi + ((size_t)(b * NK + i)) * NE + e0) =
      make_float4(acc1[0], acc1[1], acc1[2], acc1[3]);
#pragma unroll
  for (int k = 0; k < 4; ++k)
    hjT[((size_t)(b * NE + e0 + k)) * NK + i] = acc2[k] + bl[e0 + k];
}

// ---------------------------------------------------------------------------
// Kernel 2: per (b, i-tile of 8) block, 512 threads (8 waves).
//  e'_ij = sum_q [ s_q(ii,j) + 0.25*aj_q(j) ] + bias_ij      (ai term cancels
//  in softmax: row-constant). s_q = sum_{e in q} a8_e*relu(hi_ie + hjT_ej).
//  attn = softmax_j(e'); out[b][w][i] = sigmoid(sum_j attn_ij * x[b][w][j]).
// ---------------------------------------------------------------------------
__global__ __launch_bounds__(512) void k2_attn(
    const float* __restrict__ x, const float* __restrict__ a_vec,
    const float* __restrict__ bias, const float* __restrict__ hi,
    const float* __restrict__ hjT, float* __restrict__ out)
{
  __shared__ __align__(16) float smA[2304];   // hi tile 2048 | a8 256; attn reuses hi region
  __shared__ __align__(16) float smB[16384];  // sred[8][8][256] = 64 KB

  const int b    = blockIdx.x >> 5;
  const int i0   = (blockIdx.x & 31) << 3;
  const int t    = threadIdx.x;
  const int lane = t & 63, wave = t >> 6;

  // ---- stage hi tile (2048 floats) + 0.8*a ----
  {
    const float4* src = (const float4*)(hi + ((size_t)(b * NK + i0)) * NE);
    ((float4*)smA)[t] = src[t];
    if (t < 64) {
      const float4 av = ((const float4*)a_vec)[t];
      ((float4*)(smA + 2048))[t] =
          make_float4(0.8f * av.x, 0.8f * av.y, 0.8f * av.z, 0.8f * av.w);
    }
  }
  __syncthreads();

  // ---- main relu loop: wave = e-eighth q, lane -> 4 contiguous j ----
  {
    const int q = wave;
    const int j0 = lane << 2;
    float s[8][4];
#pragma unroll
    for (int ii = 0; ii < 8; ++ii)
#pragma unroll
      for (int m = 0; m < 4; ++m) s[ii][m] = 0.f;
    float aj[4] = {0.f, 0.f, 0.f, 0.f};

    const float* hjb = hjT + (size_t)b * NE * NK + j0;

#pragma unroll 2
    for (int ec = 0; ec < 8; ++ec) {
      const int e = q * 32 + ec * 4;
      float h[4][4];  // [k = e-offset][m = j-offset]
#pragma unroll
      for (int k = 0; k < 4; ++k)
        *reinterpret_cast<float4*>(h[k]) =
            *reinterpret_cast<const float4*>(hjb + (size_t)(e + k) * NK);
      float a4[4];
      *reinterpret_cast<float4*>(a4) =
          *reinterpret_cast<const float4*>(smA + 2048 + e);
#pragma unroll
      for (int k = 0; k < 4; ++k)
#pragma unroll
        for (int m = 0; m < 4; ++m) aj[m] = fmaf(a4[k], h[k][m], aj[m]);
#pragma unroll
      for (int ii = 0; ii < 8; ++ii) {
        float g[4];
        *reinterpret_cast<float4*>(g) =
            *reinterpret_cast<const float4*>(smA + ii * NE + e);
#pragma unroll
        for (int k = 0; k < 4; ++k)
#pragma unroll
          for (int m = 0; m < 4; ++m)
            s[ii][m] = fmaf(a4[k], fmaxf(g[k] + h[k][m], 0.f), s[ii][m]);
      }
    }

    // fold 0.25*aj_q into every ii slot; Sum_q then gives relu-sum + 0.25*aj.
#pragma unroll
    for (int ii = 0; ii < 8; ++ii)
      *reinterpret_cast<float4*>(&smB[(q * 8 + ii) * NK + j0]) =
          make_float4(s[ii][0] + 0.25f * aj[0], s[ii][1] + 0.25f * aj[1],
                      s[ii][2] + 0.25f * aj[2], s[ii][3] + 0.25f * aj[3]);
  }
  __syncthreads();

  // ---- softmax over j: wave = row ii ----
  {
    const int ii = wave;
    float ev[4];
    float mmax = -INFINITY;
#pragma unroll
    for (int r = 0; r < 4; ++r) {
      const int jj = lane + 64 * r;
      float v = bias[(size_t)(i0 + ii) * NK + jj];
#pragma unroll
      for (int qq = 0; qq < 8; ++qq) v += smB[(qq * 8 + ii) * NK + jj];
      ev[r] = v;
      mmax = fmaxf(mmax, v);
    }
#pragma unroll
    for (int o = 32; o; o >>= 1) mmax = fmaxf(mmax, __shfl_xor(mmax, o));
    float ssum = 0.f;
#pragma unroll
    for (int r = 0; r < 4; ++r) { ev[r] = __expf(ev[r] - mmax); ssum += ev[r]; }
#pragma unroll
    for (int o = 32; o; o >>= 1) ssum += __shfl_xor(ssum, o);
    const float inv = 1.f / ssum;
#pragma unroll
    for (int r = 0; r < 4; ++r) smA[ii * NE + lane + 64 * r] = ev[r] * inv;
  }
  __syncthreads();

  // ---- PV: thread = (w = t&127, ih = t>>7 -> ii pair {2ih, 2ih+1}) ----
  // Full j-sum in-thread (jc covers ALL 256 j's = 64 float4 chunks).
  {
    const int w = t & 127, ih = t >> 7;
    float acc0 = 0.f, acc1 = 0.f;
    const float* xr = x + (size_t)b * NWIN * NK + (size_t)w * NK;
    const float* at0 = smA + (2 * ih) * NE;
    const float* at1 = at0 + NE;
#pragma unroll 4
    for (int jc = 0; jc < 64; ++jc) {
      const float4 xv = *reinterpret_cast<const float4*>(&xr[jc * 4]);
      const float4 a0 = *reinterpret_cast<const float4*>(&at0[jc * 4]);
      const float4 a1 = *reinterpret_cast<const float4*>(&at1[jc * 4]);
      acc0 = fmaf(a0.x, xv.x, acc0); acc0 = fmaf(a0.y, xv.y, acc0);
      acc0 = fmaf(a0.z, xv.z, acc0); acc0 = fmaf(a0.w, xv.w, acc0);
      acc1 = fmaf(a1.x, xv.x, acc1); acc1 = fmaf(a1.y, xv.y, acc1);
      acc1 = fmaf(a1.z, xv.z, acc1); acc1 = fmaf(a1.w, xv.w, acc1);
    }
    float* op = out + ((size_t)(b * NWIN + w)) * NK + i0 + 2 * ih;
    op[0] = 1.f / (1.f + __expf(-acc0));
    op[1] = 1.f / (1.f + __expf(-acc1));
  }
}

}  // namespace

extern "C" void kernel_launch(void* const* d_in, const int* in_sizes, int n_in,
                              void* d_out, int out_size, void* d_ws,
                              size_t ws_size, hipStream_t stream)
{
  const float* x    = (const float*)d_in[0];  // (8,128,256)
  const float* Wlin = (const float*)d_in[1];  // (256,256)
  const float* blin = (const float*)d_in[2];  // (256,)
  const float* avec = (const float*)d_in[3];  // (256,1)
  const float* bias = (const float*)d_in[4];  // (256,256)
  float* out = (float*)d_out;                 // (8,128,256)

  float* hi  = (float*)d_ws;                   // B*K*E floats = 2 MB
  float* hjT = hi + (size_t)NB * NK * NE;      // B*E*K floats = 2 MB

  k1_proj<<<NB * (NE / 4), 256, 0, stream>>>(x, Wlin, blin, hi, hjT);
  k2_attn<<<NB * (NK / 8), 512, 0, stream>>>(x, avec, bias, hi, hjT, out);
}

// Round 7
// 34.278 us; speedup vs baseline: 1.9602x; 1.3416x over previous
//
#include <hip/hip_runtime.h>
#include <math.h>

namespace {
constexpr int NB   = 8;    // batch
constexpr int NWIN = 128;  // WIN
constexpr int NK   = 256;  // K (feature/attention dim)
constexpr int NE   = 256;  // E = 2*WIN

// ---------------------------------------------------------------------------
// Kernel 1: projections (unchanged from round 6).
//   hi [b][i][e] = sum_w x[b][w][i] * W_lin[e][w]
//   hjT[b][e][j] = sum_w x[b][w][j] * W_lin[e][WIN+w] + b_lin[e]
// ---------------------------------------------------------------------------
__global__ __launch_bounds__(256) void k1_proj(
    const float* __restrict__ x, const float* __restrict__ W,
    const float* __restrict__ bl, float* __restrict__ hi,
    float* __restrict__ hjT)
{
  const int b  = blockIdx.x >> 6;          // 0..7
  const int e0 = (blockIdx.x & 63) << 2;   // 64 groups of 4 e's
  const int i  = threadIdx.x;

  float acc1[4] = {0.f, 0.f, 0.f, 0.f};
  float acc2[4] = {0.f, 0.f, 0.f, 0.f};

  const float* xb = x + (size_t)b * NWIN * NK + i;
  const float* Wr = W + (size_t)e0 * (2 * NWIN);
#pragma unroll 8
  for (int w = 0; w < NWIN; ++w) {
    const float xv = xb[(size_t)w * NK];
#pragma unroll
    for (int k = 0; k < 4; ++k) {
      acc1[k] = fmaf(xv, Wr[k * 2 * NWIN + w], acc1[k]);
      acc2[k] = fmaf(xv, Wr[k * 2 * NWIN + NWIN + w], acc2[k]);
    }
  }

  *reinterpret_cast<float4*>(hi + ((size_t)(b * NK + i)) * NE + e0) =
      make_float4(acc1[0], acc1[1], acc1[2], acc1[3]);
#pragma unroll
  for (int k = 0; k < 4; ++k)
    hjT[((size_t)(b * NE + e0 + k)) * NK + i] = acc2[k] + bl[e0 + k];
}

// ---------------------------------------------------------------------------
// Kernel 2: per (b, i-tile of 4) block, 512 threads, grid = 8*64 = 512
// -> 2 blocks/CU (LDS ~38 KB), 4 waves/SIMD.
//  e'_ij = sum_q [ s_q(ii,j) + 0.25*aj_q(j) ] + bias_ij   (ai cancels in
//  softmax). s_q = sum_{e in q} a8_e*relu(hi_ie + hjT_ej).
//  attn = softmax_j(e'); out[b][w][i] = sigmoid(sum_j attn_ij * x[b][w][j]).
// ---------------------------------------------------------------------------
__global__ __launch_bounds__(512, 4) void k2_attn(
    const float* __restrict__ x, const float* __restrict__ a_vec,
    const float* __restrict__ bias, const float* __restrict__ hi,
    const float* __restrict__ hjT, float* __restrict__ out)
{
  // smA: [0..1023] hi tile (4 rows x 256), reused as attn after softmax;
  //      [1024..1279] a8 = 0.8*a.
  __shared__ __align__(16) float smA[1280];
  // smB: sred[8 q][4 ii][256 j] = 32 KB.
  __shared__ __align__(16) float smB[8192];

  const int b    = blockIdx.x >> 6;
  const int i0   = (blockIdx.x & 63) << 2;
  const int t    = threadIdx.x;
  const int lane = t & 63, wave = t >> 6;

  // ---- stage hi tile (1024 floats) + 0.8*a ----
  if (t < 256) {
    ((float4*)smA)[t] =
        ((const float4*)(hi + ((size_t)(b * NK + i0)) * NE))[t];
  } else if (t < 320) {
    const float4 av = ((const float4*)a_vec)[t - 256];
    ((float4*)(smA + 1024))[t - 256] =
        make_float4(0.8f * av.x, 0.8f * av.y, 0.8f * av.z, 0.8f * av.w);
  }
  __syncthreads();

  // ---- main relu loop: wave = e-eighth q, lane -> 4 contiguous j ----
  {
    const int q = wave;
    const int j0 = lane << 2;
    float s[4][4];
#pragma unroll
    for (int ii = 0; ii < 4; ++ii)
#pragma unroll
      for (int m = 0; m < 4; ++m) s[ii][m] = 0.f;
    float aj[4] = {0.f, 0.f, 0.f, 0.f};

    const float* hjb = hjT + (size_t)b * NE * NK + j0;

#pragma unroll 2
    for (int ec = 0; ec < 8; ++ec) {
      const int e = q * 32 + ec * 4;
      float h[4][4];  // [k = e-offset][m = j-offset]
#pragma unroll
      for (int k = 0; k < 4; ++k)
        *reinterpret_cast<float4*>(h[k]) =
            *reinterpret_cast<const float4*>(hjb + (size_t)(e + k) * NK);
      float a4[4];
      *reinterpret_cast<float4*>(a4) =
          *reinterpret_cast<const float4*>(smA + 1024 + e);
#pragma unroll
      for (int k = 0; k < 4; ++k)
#pragma unroll
        for (int m = 0; m < 4; ++m) aj[m] = fmaf(a4[k], h[k][m], aj[m]);
#pragma unroll
      for (int ii = 0; ii < 4; ++ii) {
        float g[4];
        *reinterpret_cast<float4*>(g) =
            *reinterpret_cast<const float4*>(smA + ii * NE + e);
#pragma unroll
        for (int k = 0; k < 4; ++k)
#pragma unroll
          for (int m = 0; m < 4; ++m)
            s[ii][m] = fmaf(a4[k], fmaxf(g[k] + h[k][m], 0.f), s[ii][m]);
      }
    }

    // fold 0.25*aj_q into every ii slot; Sum_q gives relu-sum + 0.25*aj.
#pragma unroll
    for (int ii = 0; ii < 4; ++ii)
      *reinterpret_cast<float4*>(&smB[(q * 4 + ii) * NK + j0]) =
          make_float4(s[ii][0] + 0.25f * aj[0], s[ii][1] + 0.25f * aj[1],
                      s[ii][2] + 0.25f * aj[2], s[ii][3] + 0.25f * aj[3]);
  }
  __syncthreads();

  // ---- softmax over j: waves 0-3, wave = row ii (overwrites hi w/ attn) ----
  if (wave < 4) {
    const int ii = wave;
    float ev[4];
    float mmax = -INFINITY;
#pragma unroll
    for (int r = 0; r < 4; ++r) {
      const int jj = lane + 64 * r;
      float v = bias[(size_t)(i0 + ii) * NK + jj];
#pragma unroll
      for (int qq = 0; qq < 8; ++qq) v += smB[(qq * 4 + ii) * NK + jj];
      ev[r] = v;
      mmax = fmaxf(mmax, v);
    }
#pragma unroll
    for (int o = 32; o; o >>= 1) mmax = fmaxf(mmax, __shfl_xor(mmax, o));
    float ssum = 0.f;
#pragma unroll
    for (int r = 0; r < 4; ++r) { ev[r] = __expf(ev[r] - mmax); ssum += ev[r]; }
#pragma unroll
    for (int o = 32; o; o >>= 1) ssum += __shfl_xor(ssum, o);
    const float inv = 1.f / ssum;
#pragma unroll
    for (int r = 0; r < 4; ++r) smA[ii * NE + lane + 64 * r] = ev[r] * inv;
  }
  __syncthreads();

  // ---- PV: thread = (w = t>>2, jq = t&3). 4-lane groups read the SAME x
  // row at 4 consecutive float4 -> 16 lines/instr (4x fewer than row-per-
  // lane). Partials combined via shfl_xor(1,2); jq==0 lane stores float4.
  {
    const int wv = t >> 2, jq = t & 3;
    float s0 = 0.f, s1 = 0.f, s2 = 0.f, s3 = 0.f;
    const float* xr = x + (size_t)b * NWIN * NK + (size_t)wv * NK;
#pragma unroll 4
    for (int jc = 0; jc < 16; ++jc) {
      const int j = jc * 16 + jq * 4;
      const float4 xv = *reinterpret_cast<const float4*>(&xr[j]);
      const float4 a0 = *reinterpret_cast<const float4*>(&smA[0 * NE + j]);
      const float4 a1 = *reinterpret_cast<const float4*>(&smA[1 * NE + j]);
      const float4 a2 = *reinterpret_cast<const float4*>(&smA[2 * NE + j]);
      const float4 a3 = *reinterpret_cast<const float4*>(&smA[3 * NE + j]);
      s0 = fmaf(a0.x, xv.x, s0); s0 = fmaf(a0.y, xv.y, s0);
      s0 = fmaf(a0.z, xv.z, s0); s0 = fmaf(a0.w, xv.w, s0);
      s1 = fmaf(a1.x, xv.x, s1); s1 = fmaf(a1.y, xv.y, s1);
      s1 = fmaf(a1.z, xv.z, s1); s1 = fmaf(a1.w, xv.w, s1);
      s2 = fmaf(a2.x, xv.x, s2); s2 = fmaf(a2.y, xv.y, s2);
      s2 = fmaf(a2.z, xv.z, s2); s2 = fmaf(a2.w, xv.w, s2);
      s3 = fmaf(a3.x, xv.x, s3); s3 = fmaf(a3.y, xv.y, s3);
      s3 = fmaf(a3.z, xv.z, s3); s3 = fmaf(a3.w, xv.w, s3);
    }
#pragma unroll
    for (int o = 1; o <= 2; o <<= 1) {
      s0 += __shfl_xor(s0, o);
      s1 += __shfl_xor(s1, o);
      s2 += __shfl_xor(s2, o);
      s3 += __shfl_xor(s3, o);
    }
    if (jq == 0) {
      float4 o4;
      o4.x = 1.f / (1.f + __expf(-s0));
      o4.y = 1.f / (1.f + __expf(-s1));
      o4.z = 1.f / (1.f + __expf(-s2));
      o4.w = 1.f / (1.f + __expf(-s3));
      *reinterpret_cast<float4*>(out + ((size_t)(b * NWIN + wv)) * NK + i0) =
          o4;
    }
  }
}

}  // namespace

extern "C" void kernel_launch(void* const* d_in, const int* in_sizes, int n_in,
                              void* d_out, int out_size, void* d_ws,
                              size_t ws_size, hipStream_t stream)
{
  const float* x    = (const float*)d_in[0];  // (8,128,256)
  const float* Wlin = (const float*)d_in[1];  // (256,256)
  const float* blin = (const float*)d_in[2];  // (256,)
  const float* avec = (const float*)d_in[3];  // (256,1)
  const float* bias = (const float*)d_in[4];  // (256,256)
  float* out = (float*)d_out;                 // (8,128,256)

  float* hi  = (float*)d_ws;                   // B*K*E floats = 2 MB
  float* hjT = hi + (size_t)NB * NK * NE;      // B*E*K floats = 2 MB

  k1_proj<<<NB * (NE / 4), 256, 0, stream>>>(x, Wlin, blin, hi, hjT);
  k2_attn<<<NB * (NK / 4), 512, 0, stream>>>(x, avec, bias, hi, hjT, out);
}